// Round 1
// baseline (604.002 us; speedup 1.0000x reference)
//
#include <hip/hip_runtime.h>

#define N_NODES 50000
#define NEG_SLOPE 0.2f

// ---------------- GEMM: C[M,N] = A[M,K] * B[K,N], fp32, 64x64 tile ----------
__global__ __launch_bounds__(256) void gemm_tile64(
    const float* __restrict__ A, const float* __restrict__ B,
    float* __restrict__ C, int M, int N, int K) {
  __shared__ float As[16][68];  // [k][m], pad 4 keeps float4 alignment
  __shared__ float Bs[16][68];  // [k][n]
  const int tid = threadIdx.x;
  const int tx = tid & 15, ty = tid >> 4;
  const int m0 = blockIdx.x * 64;
  const int n0 = blockIdx.y * 64;
  float acc[4][4] = {};
  for (int k0 = 0; k0 < K; k0 += 16) {
    // A tile: 64 m x 16 k, each thread one float4 along k
    {
      const int m = tid >> 2;        // 0..63
      const int kq = (tid & 3) * 4;  // 0,4,8,12
      const int gm = m0 + m;
      float4 v = make_float4(0.f, 0.f, 0.f, 0.f);
      if (gm < M) v = *reinterpret_cast<const float4*>(&A[(size_t)gm * K + k0 + kq]);
      As[kq + 0][m] = v.x; As[kq + 1][m] = v.y;
      As[kq + 2][m] = v.z; As[kq + 3][m] = v.w;
    }
    // B tile: 16 k x 64 n, each thread one float4 along n
    {
      const int k = tid >> 4;         // 0..15
      const int n4 = (tid & 15) * 4;  // 0..60
      float4 v = *reinterpret_cast<const float4*>(&B[(size_t)(k0 + k) * N + n0 + n4]);
      *reinterpret_cast<float4*>(&Bs[k][n4]) = v;
    }
    __syncthreads();
#pragma unroll
    for (int kk = 0; kk < 16; ++kk) {
      float4 a = *reinterpret_cast<const float4*>(&As[kk][ty * 4]);
      float4 b = *reinterpret_cast<const float4*>(&Bs[kk][tx * 4]);
      float av[4] = {a.x, a.y, a.z, a.w};
      float bv[4] = {b.x, b.y, b.z, b.w};
#pragma unroll
      for (int i = 0; i < 4; ++i)
#pragma unroll
        for (int j = 0; j < 4; ++j) acc[i][j] = fmaf(av[i], bv[j], acc[i][j]);
    }
    __syncthreads();
  }
#pragma unroll
  for (int i = 0; i < 4; ++i) {
    const int gm = m0 + ty * 4 + i;
    if (gm < M) {
      float4 o = make_float4(acc[i][0], acc[i][1], acc[i][2], acc[i][3]);
      *reinterpret_cast<float4*>(&C[(size_t)gm * N + n0 + tx * 4]) = o;
    }
  }
}

// ------------- per-node attention scores: s = <h[n,h,:], a[h,:]> ------------
template <int HEADS>
__global__ void scores_kernel(const float* __restrict__ h,
                              const float* __restrict__ a_src,
                              const float* __restrict__ a_dst,
                              float* __restrict__ s_src,
                              float* __restrict__ s_dst) {
  const int HC = HEADS * 128;
  const int n = blockIdx.x, t = threadIdx.x;
  float v = h[(size_t)n * HC + t];
  float ps = v * a_src[t];
  float pd = v * a_dst[t];
#pragma unroll
  for (int off = 32; off > 0; off >>= 1) {
    ps += __shfl_down(ps, off);
    pd += __shfl_down(pd, off);
  }
  __shared__ float red[4][2];
  const int lane = t & 63, wave = t >> 6;
  if (lane == 0) { red[wave][0] = ps; red[wave][1] = pd; }
  __syncthreads();
  if (t < HEADS) {  // each head spans 2 waves (C=128)
    s_src[n * HEADS + t] = red[2 * t][0] + red[2 * t + 1][0];
    s_dst[n * HEADS + t] = red[2 * t][1] + red[2 * t + 1][1];
  }
}

// ---------------- CSR build: histogram -> scan -> scatter -------------------
__global__ void hist_kernel(const int* __restrict__ ei, int E, int Etot,
                            int* __restrict__ counts) {
  int e = blockIdx.x * blockDim.x + threadIdx.x;
  if (e >= Etot) return;
  int d = (e < E) ? ei[E + e] : (e - E);  // self-loops appended
  atomicAdd(&counts[d], 1);
}

__global__ __launch_bounds__(1024) void scan_kernel(const int* __restrict__ counts,
                                                    int* __restrict__ rowptr, int n) {
  __shared__ int tmp[1024];
  __shared__ int carry_s;
  if (threadIdx.x == 0) { carry_s = 0; rowptr[0] = 0; }
  __syncthreads();
  for (int base = 0; base < n; base += 1024) {
    int i = base + threadIdx.x;
    int v = (i < n) ? counts[i] : 0;
    tmp[threadIdx.x] = v;
    __syncthreads();
    for (int off = 1; off < 1024; off <<= 1) {
      int t = (threadIdx.x >= off) ? tmp[threadIdx.x - off] : 0;
      __syncthreads();
      tmp[threadIdx.x] += t;
      __syncthreads();
    }
    int incl = tmp[threadIdx.x] + carry_s;
    if (i < n) rowptr[i + 1] = incl;
    __syncthreads();
    if (threadIdx.x == 1023) carry_s = incl;
    __syncthreads();
  }
}

__global__ void scatter_kernel(const int* __restrict__ ei, int E, int Etot,
                               const int* __restrict__ rowptr,
                               int* __restrict__ cursor, int* __restrict__ csr_src) {
  int e = blockIdx.x * blockDim.x + threadIdx.x;
  if (e >= Etot) return;
  int s, d;
  if (e < E) { s = ei[e]; d = ei[E + e]; } else { s = d = e - E; }
  int pos = rowptr[d] + atomicAdd(&cursor[d], 1);
  csr_src[pos] = s;
}

// ---- layer-0 aggregation: softmax-weighted sum + bias + ELU, H=2, C=128 ----
// exp WITHOUT max-subtraction: softmax is shift-invariant, scores are small.
__global__ __launch_bounds__(64) void agg0_kernel(
    const float4* __restrict__ h0,  // [N, 64] float4 (256 floats/row)
    const float* __restrict__ s_src, const float* __restrict__ s_dst,
    const int* __restrict__ rowptr, const int* __restrict__ csr_src,
    const float* __restrict__ b0, float* __restrict__ hE) {
  const int n = blockIdx.x, t = threadIdx.x;
  const int hd = t >> 5;  // lanes 0-31 head 0, 32-63 head 1
  const float sd = s_dst[n * 2 + hd];
  float4 acc = make_float4(0.f, 0.f, 0.f, 0.f);
  float den = 0.f;
  const int p1 = rowptr[n + 1];
  for (int p = rowptr[n]; p < p1; ++p) {
    const int s = csr_src[p];
    float e = s_src[s * 2 + hd] + sd;
    e = (e > 0.f) ? e : NEG_SLOPE * e;
    const float w = __expf(e);
    den += w;
    const float4 hv = h0[(size_t)s * 64 + t];
    acc.x = fmaf(w, hv.x, acc.x);
    acc.y = fmaf(w, hv.y, acc.y);
    acc.z = fmaf(w, hv.z, acc.z);
    acc.w = fmaf(w, hv.w, acc.w);
  }
  const float inv = 1.f / den;  // den >= exp(self-loop weight) > 0
  const float4 bv = reinterpret_cast<const float4*>(b0)[t];
  float o[4] = {fmaf(acc.x, inv, bv.x), fmaf(acc.y, inv, bv.y),
                fmaf(acc.z, inv, bv.z), fmaf(acc.w, inv, bv.w)};
#pragma unroll
  for (int i = 0; i < 4; ++i) o[i] = (o[i] > 0.f) ? o[i] : (__expf(o[i]) - 1.f);
  reinterpret_cast<float4*>(hE)[(size_t)n * 64 + t] = make_float4(o[0], o[1], o[2], o[3]);
}

// ---- layer-1 aggregation + bias + residual, H=1, C=128 ---------------------
__global__ __launch_bounds__(64) void agg1_kernel(
    const float2* __restrict__ h1,  // [N, 64] float2 (128 floats/row)
    const float* __restrict__ s_src, const float* __restrict__ s_dst,
    const int* __restrict__ rowptr, const int* __restrict__ csr_src,
    const float* __restrict__ b1, const float2* __restrict__ x,
    float2* __restrict__ out) {
  const int n = blockIdx.x, t = threadIdx.x;
  const float sd = s_dst[n];
  float2 acc = make_float2(0.f, 0.f);
  float den = 0.f;
  const int p1 = rowptr[n + 1];
  for (int p = rowptr[n]; p < p1; ++p) {
    const int s = csr_src[p];
    float e = s_src[s] + sd;
    e = (e > 0.f) ? e : NEG_SLOPE * e;
    const float w = __expf(e);
    den += w;
    const float2 hv = h1[(size_t)s * 64 + t];
    acc.x = fmaf(w, hv.x, acc.x);
    acc.y = fmaf(w, hv.y, acc.y);
  }
  const float inv = 1.f / den;
  const float2 bv = reinterpret_cast<const float2*>(b1)[t];
  const float2 xv = x[(size_t)n * 64 + t];
  out[(size_t)n * 64 + t] =
      make_float2(xv.x + fmaf(acc.x, inv, bv.x), xv.y + fmaf(acc.y, inv, bv.y));
}

extern "C" void kernel_launch(void* const* d_in, const int* in_sizes, int n_in,
                              void* d_out, int out_size, void* d_ws, size_t ws_size,
                              hipStream_t stream) {
  const float* x      = (const float*)d_in[0];
  const float* W0     = (const float*)d_in[1];
  const float* a_src0 = (const float*)d_in[2];
  const float* a_dst0 = (const float*)d_in[3];
  const float* b0     = (const float*)d_in[4];
  const float* W1     = (const float*)d_in[5];
  const float* a_src1 = (const float*)d_in[6];
  const float* a_dst1 = (const float*)d_in[7];
  const float* b1     = (const float*)d_in[8];
  const int*   ei     = (const int*)d_in[9];
  const int E = in_sizes[9] / 2;          // 800000
  const int Etot = E + N_NODES;           // + self loops
  float* out = (float*)d_out;
  (void)n_in; (void)out_size; (void)ws_size;

  char* ws = (char*)d_ws;
  size_t off = 0;
  auto alloc = [&](size_t bytes) -> char* {
    char* p = ws + off;
    off += (bytes + 255) & ~(size_t)255;
    return p;
  };
  float* h0   = (float*)alloc((size_t)N_NODES * 256 * 4);  // 51.2 MB
  float* hE   = (float*)alloc((size_t)N_NODES * 256 * 4);  // 51.2 MB
  float* h1   = (float*)alloc((size_t)N_NODES * 128 * 4);  // 25.6 MB
  float* ss0  = (float*)alloc((size_t)N_NODES * 2 * 4);
  float* sd0  = (float*)alloc((size_t)N_NODES * 2 * 4);
  float* ss1  = (float*)alloc((size_t)N_NODES * 4);
  float* sd1  = (float*)alloc((size_t)N_NODES * 4);
  int* counts = (int*)alloc((size_t)N_NODES * 4);
  int* cursor = (int*)alloc((size_t)N_NODES * 4);
  int* rowptr = (int*)alloc((size_t)(N_NODES + 1) * 4);
  int* csr    = (int*)alloc((size_t)Etot * 4);             // 3.4 MB

  hipMemsetAsync(counts, 0, (size_t)N_NODES * 4, stream);
  hipMemsetAsync(cursor, 0, (size_t)N_NODES * 4, stream);

  // ---- layer 0 ----
  dim3 g0((N_NODES + 63) / 64, 256 / 64);
  gemm_tile64<<<g0, 256, 0, stream>>>(x, W0, h0, N_NODES, 256, 128);
  scores_kernel<2><<<N_NODES, 256, 0, stream>>>(h0, a_src0, a_dst0, ss0, sd0);

  // ---- CSR build (shared by both layers: same edge set) ----
  hist_kernel<<<(Etot + 255) / 256, 256, 0, stream>>>(ei, E, Etot, counts);
  scan_kernel<<<1, 1024, 0, stream>>>(counts, rowptr, N_NODES);
  scatter_kernel<<<(Etot + 255) / 256, 256, 0, stream>>>(ei, E, Etot, rowptr, cursor, csr);

  agg0_kernel<<<N_NODES, 64, 0, stream>>>((const float4*)h0, ss0, sd0, rowptr, csr, b0, hE);

  // ---- layer 1 ----
  dim3 g1((N_NODES + 63) / 64, 128 / 64);
  gemm_tile64<<<g1, 256, 0, stream>>>(hE, W1, h1, N_NODES, 128, 256);
  scores_kernel<1><<<N_NODES, 128, 0, stream>>>(h1, a_src1, a_dst1, ss1, sd1);
  agg1_kernel<<<N_NODES, 64, 0, stream>>>((const float2*)h1, ss1, sd1, rowptr, csr, b1,
                                          (const float2*)x, (float2*)out);
}

// Round 2
// 462.040 us; speedup vs baseline: 1.3073x; 1.3073x over previous
//
#include <hip/hip_runtime.h>

#define N_NODES 50000
#define NEG_SLOPE 0.2f

typedef short s8v __attribute__((ext_vector_type(8)));
typedef float f4v __attribute__((ext_vector_type(4)));

// ---- bf16 helpers (RNE), bit-manip to avoid header/type friction ----------
__device__ __forceinline__ ushort f2bf(float f) {
  union { float f; unsigned u; } v; v.f = f;
  return (ushort)((v.u + 0x7FFFu + ((v.u >> 16) & 1u)) >> 16);
}
__device__ __forceinline__ float bf2f(ushort h) {
  union { unsigned u; float f; } v; v.u = ((unsigned)h) << 16;
  return v.f;
}

// ---- fp32 -> bf16 bulk convert (x) ----------------------------------------
__global__ void conv_x_kernel(const float* __restrict__ in, ushort* __restrict__ out, int n4) {
  int i = blockIdx.x * blockDim.x + threadIdx.x;
  if (i >= n4) return;
  float4 v = reinterpret_cast<const float4*>(in)[i];
  ushort4 o; o.x = f2bf(v.x); o.y = f2bf(v.y); o.z = f2bf(v.z); o.w = f2bf(v.w);
  reinterpret_cast<ushort4*>(out)[i] = o;
}

// ---- weight transpose+convert: in[R][C] fp32 -> out[C][R] bf16 ------------
__global__ void convT_kernel(const float* __restrict__ in, ushort* __restrict__ out,
                             int R, int C) {
  int i = blockIdx.x * blockDim.x + threadIdx.x;
  if (i >= R * C) return;
  int r = i / C, c = i % C;
  out[c * R + r] = f2bf(in[i]);
}

// ---- MFMA GEMM: C[M,N]=A[M,K]*B[K,N]; A bf16 [M,K], BT bf16 [N,K] ---------
// block = 256 thr (4 waves), tile 64(M)x64(N), BK=128 staged in LDS.
__global__ __launch_bounds__(256) void gemm_mfma(
    const ushort* __restrict__ A, const ushort* __restrict__ BT,
    ushort* __restrict__ C, int M, int N, int K) {
  __shared__ ushort As[64][136];  // +8 pad: keeps 16B align, 2-way banks (free)
  __shared__ ushort Bs[64][136];
  const int tid = threadIdx.x;
  const int w = tid >> 6, lane = tid & 63;
  const int q = lane >> 4, r16 = lane & 15;
  const int m0 = blockIdx.x * 64, n0 = blockIdx.y * 64;
  f4v acc[4] = {};
  for (int kc = 0; kc < K; kc += 128) {
    // stage A tile 64x128 (guarded on M), B tile 64x128 (N exact)
#pragma unroll
    for (int i = 0; i < 4; ++i) {
      int c = tid + 256 * i;
      int row = c >> 4, ko = (c & 15) * 8;
      int gm = m0 + row;
      s8v va = {};
      if (gm < M) va = *reinterpret_cast<const s8v*>(&A[(size_t)gm * K + kc + ko]);
      *reinterpret_cast<s8v*>(&As[row][ko]) = va;
      s8v vb = *reinterpret_cast<const s8v*>(&BT[(size_t)(n0 + row) * K + kc + ko]);
      *reinterpret_cast<s8v*>(&Bs[row][ko]) = vb;
    }
    __syncthreads();
#pragma unroll
    for (int ks = 0; ks < 4; ++ks) {
      s8v af = *reinterpret_cast<const s8v*>(&As[w * 16 + r16][ks * 32 + q * 8]);
#pragma unroll
      for (int nt = 0; nt < 4; ++nt) {
        s8v bf = *reinterpret_cast<const s8v*>(&Bs[nt * 16 + r16][ks * 32 + q * 8]);
        acc[nt] = __builtin_amdgcn_mfma_f32_16x16x32_bf16(af, bf, acc[nt], 0, 0, 0);
      }
    }
    __syncthreads();
  }
  // D layout: row=(lane>>4)*4+reg, col=lane&15 within each 16x16 tile
#pragma unroll
  for (int nt = 0; nt < 4; ++nt)
#pragma unroll
    for (int r = 0; r < 4; ++r) {
      int gm = m0 + w * 16 + q * 4 + r;
      if (gm < M) C[(size_t)gm * N + n0 + nt * 16 + r16] = f2bf(acc[nt][r]);
    }
}

// ---- per-node attention scores: s = <h[n,hd,:], a[hd,:]>, h bf16 ----------
template <int HC>
__global__ void scores_kernel(const ushort* __restrict__ h,
                              const float* __restrict__ a_src,
                              const float* __restrict__ a_dst,
                              float* __restrict__ s_src,
                              float* __restrict__ s_dst) {
  const int HEADS = HC / 128;
  const int n = blockIdx.x, t = threadIdx.x;
  float v = bf2f(h[(size_t)n * HC + t]);
  float ps = v * a_src[t];
  float pd = v * a_dst[t];
#pragma unroll
  for (int off = 32; off > 0; off >>= 1) {
    ps += __shfl_down(ps, off);
    pd += __shfl_down(pd, off);
  }
  __shared__ float red[4][2];
  const int lane = t & 63, wave = t >> 6;
  if (lane == 0) { red[wave][0] = ps; red[wave][1] = pd; }
  __syncthreads();
  if (t < HEADS) {  // each head spans 2 waves (C=128)
    s_src[n * HEADS + t] = red[2 * t][0] + red[2 * t + 1][0];
    s_dst[n * HEADS + t] = red[2 * t][1] + red[2 * t + 1][1];
  }
}

// ---------------- CSR build: histogram -> scan -> scatter -------------------
__global__ void hist_kernel(const int* __restrict__ ei, int E, int Etot,
                            int* __restrict__ counts) {
  int e = blockIdx.x * blockDim.x + threadIdx.x;
  if (e >= Etot) return;
  int d = (e < E) ? ei[E + e] : (e - E);
  atomicAdd(&counts[d], 1);
}

__global__ __launch_bounds__(1024) void scan_kernel(const int* __restrict__ counts,
                                                    int* __restrict__ rowptr, int n) {
  __shared__ int tmp[1024];
  __shared__ int carry_s;
  if (threadIdx.x == 0) { carry_s = 0; rowptr[0] = 0; }
  __syncthreads();
  for (int base = 0; base < n; base += 1024) {
    int i = base + threadIdx.x;
    int v = (i < n) ? counts[i] : 0;
    tmp[threadIdx.x] = v;
    __syncthreads();
    for (int off = 1; off < 1024; off <<= 1) {
      int t = (threadIdx.x >= off) ? tmp[threadIdx.x - off] : 0;
      __syncthreads();
      tmp[threadIdx.x] += t;
      __syncthreads();
    }
    int incl = tmp[threadIdx.x] + carry_s;
    if (i < n) rowptr[i + 1] = incl;
    __syncthreads();
    if (threadIdx.x == 1023) carry_s = incl;
    __syncthreads();
  }
}

__global__ void scatter_kernel(const int* __restrict__ ei, int E, int Etot,
                               const int* __restrict__ rowptr,
                               int* __restrict__ cursor, int* __restrict__ csr_src) {
  int e = blockIdx.x * blockDim.x + threadIdx.x;
  if (e >= Etot) return;
  int s, d;
  if (e < E) { s = ei[e]; d = ei[E + e]; } else { s = d = e - E; }
  int pos = rowptr[d] + atomicAdd(&cursor[d], 1);
  csr_src[pos] = s;
}

// ---- layer-0 aggregation (bf16 gather) + bias + ELU -> hE bf16 ------------
// softmax without max-subtraction: shift-invariant, scores bounded small.
__global__ __launch_bounds__(64) void agg0_kernel(
    const ushort* __restrict__ h0,  // [N,256] bf16
    const float* __restrict__ s_src, const float* __restrict__ s_dst,
    const int* __restrict__ rowptr, const int* __restrict__ csr_src,
    const float* __restrict__ b0, ushort* __restrict__ hE) {
  const int n = blockIdx.x, t = threadIdx.x;
  const int hd = t >> 5;  // channel block t*4 : head = (t*4)>>7
  const float sd = s_dst[n * 2 + hd];
  float a0 = 0.f, a1 = 0.f, a2 = 0.f, a3 = 0.f, den = 0.f;
  const int p1 = rowptr[n + 1];
  for (int p = rowptr[n]; p < p1; ++p) {
    const int s = csr_src[p];
    float e = s_src[s * 2 + hd] + sd;
    e = (e > 0.f) ? e : NEG_SLOPE * e;
    const float wgt = __expf(e);
    den += wgt;
    ushort4 hv = *reinterpret_cast<const ushort4*>(&h0[(size_t)s * 256 + t * 4]);
    a0 = fmaf(wgt, bf2f(hv.x), a0);
    a1 = fmaf(wgt, bf2f(hv.y), a1);
    a2 = fmaf(wgt, bf2f(hv.z), a2);
    a3 = fmaf(wgt, bf2f(hv.w), a3);
  }
  const float inv = 1.f / den;
  const float4 bv = reinterpret_cast<const float4*>(b0)[t];
  float o[4] = {fmaf(a0, inv, bv.x), fmaf(a1, inv, bv.y),
                fmaf(a2, inv, bv.z), fmaf(a3, inv, bv.w)};
#pragma unroll
  for (int i = 0; i < 4; ++i) o[i] = (o[i] > 0.f) ? o[i] : (__expf(o[i]) - 1.f);
  ushort4 ov; ov.x = f2bf(o[0]); ov.y = f2bf(o[1]); ov.z = f2bf(o[2]); ov.w = f2bf(o[3]);
  *reinterpret_cast<ushort4*>(&hE[(size_t)n * 256 + t * 4]) = ov;
}

// ---- layer-1 aggregation (bf16 gather) + bias + residual -> out fp32 ------
__global__ __launch_bounds__(64) void agg1_kernel(
    const ushort* __restrict__ h1,  // [N,128] bf16
    const float* __restrict__ s_src, const float* __restrict__ s_dst,
    const int* __restrict__ rowptr, const int* __restrict__ csr_src,
    const float* __restrict__ b1, const float2* __restrict__ x,
    float2* __restrict__ out) {
  const int n = blockIdx.x, t = threadIdx.x;
  const float sd = s_dst[n];
  float a0 = 0.f, a1 = 0.f, den = 0.f;
  const int p1 = rowptr[n + 1];
  for (int p = rowptr[n]; p < p1; ++p) {
    const int s = csr_src[p];
    float e = s_src[s] + sd;
    e = (e > 0.f) ? e : NEG_SLOPE * e;
    const float wgt = __expf(e);
    den += wgt;
    ushort2 hv = *reinterpret_cast<const ushort2*>(&h1[(size_t)s * 128 + t * 2]);
    a0 = fmaf(wgt, bf2f(hv.x), a0);
    a1 = fmaf(wgt, bf2f(hv.y), a1);
  }
  const float inv = 1.f / den;
  const float2 bv = reinterpret_cast<const float2*>(b1)[t];
  const float2 xv = x[(size_t)n * 64 + t];
  out[(size_t)n * 64 + t] =
      make_float2(xv.x + fmaf(a0, inv, bv.x), xv.y + fmaf(a1, inv, bv.y));
}

extern "C" void kernel_launch(void* const* d_in, const int* in_sizes, int n_in,
                              void* d_out, int out_size, void* d_ws, size_t ws_size,
                              hipStream_t stream) {
  const float* x      = (const float*)d_in[0];
  const float* W0     = (const float*)d_in[1];
  const float* a_src0 = (const float*)d_in[2];
  const float* a_dst0 = (const float*)d_in[3];
  const float* b0     = (const float*)d_in[4];
  const float* W1     = (const float*)d_in[5];
  const float* a_src1 = (const float*)d_in[6];
  const float* a_dst1 = (const float*)d_in[7];
  const float* b1     = (const float*)d_in[8];
  const int*   ei     = (const int*)d_in[9];
  const int E = in_sizes[9] / 2;
  const int Etot = E + N_NODES;
  float* out = (float*)d_out;
  (void)n_in; (void)out_size; (void)ws_size;

  char* ws = (char*)d_ws;
  size_t off = 0;
  auto alloc = [&](size_t bytes) -> char* {
    char* p = ws + off;
    off += (bytes + 255) & ~(size_t)255;
    return p;
  };
  ushort* xb   = (ushort*)alloc((size_t)N_NODES * 128 * 2);  // 12.8 MB
  ushort* h0b  = (ushort*)alloc((size_t)N_NODES * 256 * 2);  // 25.6 MB
  ushort* hEb  = (ushort*)alloc((size_t)N_NODES * 256 * 2);  // 25.6 MB
  ushort* h1b  = (ushort*)alloc((size_t)N_NODES * 128 * 2);  // 12.8 MB
  ushort* W0T  = (ushort*)alloc((size_t)256 * 128 * 2);
  ushort* W1T  = (ushort*)alloc((size_t)128 * 256 * 2);
  float* ss0   = (float*)alloc((size_t)N_NODES * 2 * 4);
  float* sd0   = (float*)alloc((size_t)N_NODES * 2 * 4);
  float* ss1   = (float*)alloc((size_t)N_NODES * 4);
  float* sd1   = (float*)alloc((size_t)N_NODES * 4);
  int* counts  = (int*)alloc((size_t)N_NODES * 4);
  int* cursor  = (int*)alloc((size_t)N_NODES * 4);
  int* rowptr  = (int*)alloc((size_t)(N_NODES + 1) * 4);
  int* csr     = (int*)alloc((size_t)Etot * 4);

  hipMemsetAsync(counts, 0, (size_t)N_NODES * 4, stream);
  hipMemsetAsync(cursor, 0, (size_t)N_NODES * 4, stream);

  // ---- prep: bf16 conversions ----
  int n4 = N_NODES * 128 / 4;
  conv_x_kernel<<<(n4 + 255) / 256, 256, 0, stream>>>(x, xb, n4);
  convT_kernel<<<(128 * 256 + 255) / 256, 256, 0, stream>>>(W0, W0T, 128, 256);
  convT_kernel<<<(256 * 128 + 255) / 256, 256, 0, stream>>>(W1, W1T, 256, 128);

  // ---- CSR build (shared by both layers) ----
  hist_kernel<<<(Etot + 255) / 256, 256, 0, stream>>>(ei, E, Etot, counts);
  scan_kernel<<<1, 1024, 0, stream>>>(counts, rowptr, N_NODES);
  scatter_kernel<<<(Etot + 255) / 256, 256, 0, stream>>>(ei, E, Etot, rowptr, cursor, csr);

  // ---- layer 0 ----
  dim3 g0((N_NODES + 63) / 64, 256 / 64);
  gemm_mfma<<<g0, 256, 0, stream>>>(xb, W0T, h0b, N_NODES, 256, 128);
  scores_kernel<256><<<N_NODES, 256, 0, stream>>>(h0b, a_src0, a_dst0, ss0, sd0);
  agg0_kernel<<<N_NODES, 64, 0, stream>>>(h0b, ss0, sd0, rowptr, csr, b0, hEb);

  // ---- layer 1 ----
  dim3 g1((N_NODES + 63) / 64, 128 / 64);
  gemm_mfma<<<g1, 256, 0, stream>>>(hEb, W1T, h1b, N_NODES, 128, 256);
  scores_kernel<128><<<N_NODES, 128, 0, stream>>>(h1b, a_src1, a_dst1, ss1, sd1);
  agg1_kernel<<<N_NODES, 64, 0, stream>>>(h1b, ss1, sd1, rowptr, csr, b1,
                                          (const float2*)x, (float2*)out);
}

// Round 3
// 384.270 us; speedup vs baseline: 1.5718x; 1.2024x over previous
//
#include <hip/hip_runtime.h>

#define N_NODES 50000
#define NEG_SLOPE 0.2f

typedef short s8v __attribute__((ext_vector_type(8)));
typedef float f4v __attribute__((ext_vector_type(4)));

// ---- bf16 helpers (RNE), bit-manip to avoid header/type friction ----------
__device__ __forceinline__ ushort f2bf(float f) {
  union { float f; unsigned u; } v; v.f = f;
  return (ushort)((v.u + 0x7FFFu + ((v.u >> 16) & 1u)) >> 16);
}
__device__ __forceinline__ float bf2f(ushort h) {
  union { unsigned u; float f; } v; v.u = ((unsigned)h) << 16;
  return v.f;
}

// ---- fp32 -> bf16 bulk convert (x) ----------------------------------------
__global__ void conv_x_kernel(const float* __restrict__ in, ushort* __restrict__ out, int n4) {
  int i = blockIdx.x * blockDim.x + threadIdx.x;
  if (i >= n4) return;
  float4 v = reinterpret_cast<const float4*>(in)[i];
  ushort4 o; o.x = f2bf(v.x); o.y = f2bf(v.y); o.z = f2bf(v.z); o.w = f2bf(v.w);
  reinterpret_cast<ushort4*>(out)[i] = o;
}

// ---- weight transpose+convert: in[R][C] fp32 -> out[C][R] bf16 ------------
__global__ void convT_kernel(const float* __restrict__ in, ushort* __restrict__ out,
                             int R, int C) {
  int i = blockIdx.x * blockDim.x + threadIdx.x;
  if (i >= R * C) return;
  int r = i / C, c = i % C;
  out[c * R + r] = f2bf(in[i]);
}

// ---- MFMA GEMM: C[M,N]=A[M,K]*B[K,N]; A bf16 [M,K], BT bf16 [N,K] ---------
__global__ __launch_bounds__(256) void gemm_mfma(
    const ushort* __restrict__ A, const ushort* __restrict__ BT,
    ushort* __restrict__ C, int M, int N, int K) {
  __shared__ ushort As[64][136];  // +8 pad: keeps 16B align, 2-way banks (free)
  __shared__ ushort Bs[64][136];
  const int tid = threadIdx.x;
  const int w = tid >> 6, lane = tid & 63;
  const int q = lane >> 4, r16 = lane & 15;
  const int m0 = blockIdx.x * 64, n0 = blockIdx.y * 64;
  f4v acc[4] = {};
  for (int kc = 0; kc < K; kc += 128) {
#pragma unroll
    for (int i = 0; i < 4; ++i) {
      int c = tid + 256 * i;
      int row = c >> 4, ko = (c & 15) * 8;
      int gm = m0 + row;
      s8v va = {};
      if (gm < M) va = *reinterpret_cast<const s8v*>(&A[(size_t)gm * K + kc + ko]);
      *reinterpret_cast<s8v*>(&As[row][ko]) = va;
      s8v vb = *reinterpret_cast<const s8v*>(&BT[(size_t)(n0 + row) * K + kc + ko]);
      *reinterpret_cast<s8v*>(&Bs[row][ko]) = vb;
    }
    __syncthreads();
#pragma unroll
    for (int ks = 0; ks < 4; ++ks) {
      s8v af = *reinterpret_cast<const s8v*>(&As[w * 16 + r16][ks * 32 + q * 8]);
#pragma unroll
      for (int nt = 0; nt < 4; ++nt) {
        s8v bf = *reinterpret_cast<const s8v*>(&Bs[nt * 16 + r16][ks * 32 + q * 8]);
        acc[nt] = __builtin_amdgcn_mfma_f32_16x16x32_bf16(af, bf, acc[nt], 0, 0, 0);
      }
    }
    __syncthreads();
  }
#pragma unroll
  for (int nt = 0; nt < 4; ++nt)
#pragma unroll
    for (int r = 0; r < 4; ++r) {
      int gm = m0 + w * 16 + q * 4 + r;
      if (gm < M) C[(size_t)gm * N + n0 + nt * 16 + r16] = f2bf(acc[nt][r]);
    }
}

// ---- per-node attention scores: s = <h[n,hd,:], a[hd,:]>, h bf16 ----------
template <int HC>
__global__ void scores_kernel(const ushort* __restrict__ h,
                              const float* __restrict__ a_src,
                              const float* __restrict__ a_dst,
                              float* __restrict__ s_src,
                              float* __restrict__ s_dst) {
  const int HEADS = HC / 128;
  const int n = blockIdx.x, t = threadIdx.x;
  float v = bf2f(h[(size_t)n * HC + t]);
  float ps = v * a_src[t];
  float pd = v * a_dst[t];
#pragma unroll
  for (int off = 32; off > 0; off >>= 1) {
    ps += __shfl_down(ps, off);
    pd += __shfl_down(pd, off);
  }
  __shared__ float red[4][2];
  const int lane = t & 63, wave = t >> 6;
  if (lane == 0) { red[wave][0] = ps; red[wave][1] = pd; }
  __syncthreads();
  if (t < HEADS) {
    s_src[n * HEADS + t] = red[2 * t][0] + red[2 * t + 1][0];
    s_dst[n * HEADS + t] = red[2 * t][1] + red[2 * t + 1][1];
  }
}

// ---------------- CSR build: histogram -> 3-pass scan -> scatter ------------
__global__ void hist_kernel(const int* __restrict__ ei, int E, int Etot,
                            int* __restrict__ counts) {
  int e = blockIdx.x * blockDim.x + threadIdx.x;
  if (e >= Etot) return;
  int d = (e < E) ? ei[E + e] : (e - E);
  atomicAdd(&counts[d], 1);
}

// pass 1: per-block (1024-wide) inclusive scan + block sums
__global__ __launch_bounds__(1024) void scan1_kernel(const int* __restrict__ counts,
                                                     int* __restrict__ partial,
                                                     int* __restrict__ blocksums, int n) {
  __shared__ int tmp[1024];
  int i = blockIdx.x * 1024 + threadIdx.x;
  int v = (i < n) ? counts[i] : 0;
  tmp[threadIdx.x] = v;
  __syncthreads();
  for (int off = 1; off < 1024; off <<= 1) {
    int t = (threadIdx.x >= off) ? tmp[threadIdx.x - off] : 0;
    __syncthreads();
    tmp[threadIdx.x] += t;
    __syncthreads();
  }
  if (i < n) partial[i] = tmp[threadIdx.x];
  if (threadIdx.x == 1023) blocksums[blockIdx.x] = tmp[1023];
}

// pass 2: single-wave inclusive scan of block sums (nb <= 64)
__global__ __launch_bounds__(64) void scan2_kernel(int* __restrict__ blocksums, int nb) {
  int t = threadIdx.x;
  int v = (t < nb) ? blocksums[t] : 0;
#pragma unroll
  for (int off = 1; off < 64; off <<= 1) {
    int u = __shfl_up(v, off);
    if (t >= off) v += u;
  }
  if (t < nb) blocksums[t] = v;
}

// pass 3: add block offsets, produce rowptr
__global__ void scan3_kernel(const int* __restrict__ partial,
                             const int* __restrict__ blocksums,
                             int* __restrict__ rowptr, int n) {
  int i = blockIdx.x * blockDim.x + threadIdx.x;
  if (i == 0) rowptr[0] = 0;
  if (i < n) {
    int b = i >> 10;
    int add = (b > 0) ? blocksums[b - 1] : 0;
    rowptr[i + 1] = partial[i] + add;
  }
}

__global__ void scatter_kernel(const int* __restrict__ ei, int E, int Etot,
                               const int* __restrict__ rowptr,
                               int* __restrict__ cursor, int* __restrict__ csr_src) {
  int e = blockIdx.x * blockDim.x + threadIdx.x;
  if (e >= Etot) return;
  int s, d;
  if (e < E) { s = ei[e]; d = ei[E + e]; } else { s = d = e - E; }
  int pos = rowptr[d] + atomicAdd(&cursor[d], 1);
  csr_src[pos] = s;
}

// ---- layer-0 aggregation (bf16 gather) + bias + ELU -> hE bf16 ------------
__global__ __launch_bounds__(64) void agg0_kernel(
    const ushort* __restrict__ h0,  // [N,256] bf16
    const float* __restrict__ s_src, const float* __restrict__ s_dst,
    const int* __restrict__ rowptr, const int* __restrict__ csr_src,
    const float* __restrict__ b0, ushort* __restrict__ hE) {
  const int n = blockIdx.x, t = threadIdx.x;
  const int hd = t >> 5;
  const float sd = s_dst[n * 2 + hd];
  float a0 = 0.f, a1 = 0.f, a2 = 0.f, a3 = 0.f, den = 0.f;
  const int p1 = rowptr[n + 1];
  for (int p = rowptr[n]; p < p1; ++p) {
    const int s = csr_src[p];
    float e = s_src[s * 2 + hd] + sd;
    e = (e > 0.f) ? e : NEG_SLOPE * e;
    const float wgt = __expf(e);
    den += wgt;
    ushort4 hv = *reinterpret_cast<const ushort4*>(&h0[(size_t)s * 256 + t * 4]);
    a0 = fmaf(wgt, bf2f(hv.x), a0);
    a1 = fmaf(wgt, bf2f(hv.y), a1);
    a2 = fmaf(wgt, bf2f(hv.z), a2);
    a3 = fmaf(wgt, bf2f(hv.w), a3);
  }
  const float inv = 1.f / den;
  const float4 bv = reinterpret_cast<const float4*>(b0)[t];
  float o[4] = {fmaf(a0, inv, bv.x), fmaf(a1, inv, bv.y),
                fmaf(a2, inv, bv.z), fmaf(a3, inv, bv.w)};
#pragma unroll
  for (int i = 0; i < 4; ++i) o[i] = (o[i] > 0.f) ? o[i] : (__expf(o[i]) - 1.f);
  ushort4 ov; ov.x = f2bf(o[0]); ov.y = f2bf(o[1]); ov.z = f2bf(o[2]); ov.w = f2bf(o[3]);
  *reinterpret_cast<ushort4*>(&hE[(size_t)n * 256 + t * 4]) = ov;
}

// ---- layer-1 aggregation (bf16 gather) + bias + residual -> out fp32 ------
__global__ __launch_bounds__(64) void agg1_kernel(
    const ushort* __restrict__ h1,  // [N,128] bf16
    const float* __restrict__ s_src, const float* __restrict__ s_dst,
    const int* __restrict__ rowptr, const int* __restrict__ csr_src,
    const float* __restrict__ b1, const float2* __restrict__ x,
    float2* __restrict__ out) {
  const int n = blockIdx.x, t = threadIdx.x;
  const float sd = s_dst[n];
  float a0 = 0.f, a1 = 0.f, den = 0.f;
  const int p1 = rowptr[n + 1];
  for (int p = rowptr[n]; p < p1; ++p) {
    const int s = csr_src[p];
    float e = s_src[s] + sd;
    e = (e > 0.f) ? e : NEG_SLOPE * e;
    const float wgt = __expf(e);
    den += wgt;
    ushort2 hv = *reinterpret_cast<const ushort2*>(&h1[(size_t)s * 128 + t * 2]);
    a0 = fmaf(wgt, bf2f(hv.x), a0);
    a1 = fmaf(wgt, bf2f(hv.y), a1);
  }
  const float inv = 1.f / den;
  const float2 bv = reinterpret_cast<const float2*>(b1)[t];
  const float2 xv = x[(size_t)n * 64 + t];
  out[(size_t)n * 64 + t] =
      make_float2(xv.x + fmaf(a0, inv, bv.x), xv.y + fmaf(a1, inv, bv.y));
}

extern "C" void kernel_launch(void* const* d_in, const int* in_sizes, int n_in,
                              void* d_out, int out_size, void* d_ws, size_t ws_size,
                              hipStream_t stream) {
  const float* x      = (const float*)d_in[0];
  const float* W0     = (const float*)d_in[1];
  const float* a_src0 = (const float*)d_in[2];
  const float* a_dst0 = (const float*)d_in[3];
  const float* b0     = (const float*)d_in[4];
  const float* W1     = (const float*)d_in[5];
  const float* a_src1 = (const float*)d_in[6];
  const float* a_dst1 = (const float*)d_in[7];
  const float* b1     = (const float*)d_in[8];
  const int*   ei     = (const int*)d_in[9];
  const int E = in_sizes[9] / 2;
  const int Etot = E + N_NODES;
  float* out = (float*)d_out;
  (void)n_in; (void)out_size; (void)ws_size;

  char* ws = (char*)d_ws;
  size_t off = 0;
  auto alloc = [&](size_t bytes) -> char* {
    char* p = ws + off;
    off += (bytes + 255) & ~(size_t)255;
    return p;
  };
  ushort* xb   = (ushort*)alloc((size_t)N_NODES * 128 * 2);
  ushort* h0b  = (ushort*)alloc((size_t)N_NODES * 256 * 2);
  ushort* hEb  = (ushort*)alloc((size_t)N_NODES * 256 * 2);
  ushort* h1b  = (ushort*)alloc((size_t)N_NODES * 128 * 2);
  ushort* W0T  = (ushort*)alloc((size_t)256 * 128 * 2);
  ushort* W1T  = (ushort*)alloc((size_t)128 * 256 * 2);
  float* ss0   = (float*)alloc((size_t)N_NODES * 2 * 4);
  float* sd0   = (float*)alloc((size_t)N_NODES * 2 * 4);
  float* ss1   = (float*)alloc((size_t)N_NODES * 4);
  float* sd1   = (float*)alloc((size_t)N_NODES * 4);
  int* counts  = (int*)alloc((size_t)N_NODES * 4);
  int* cursor  = (int*)alloc((size_t)N_NODES * 4);
  int* rowptr  = (int*)alloc((size_t)(N_NODES + 1) * 4);
  int* partial = (int*)alloc((size_t)N_NODES * 4);
  int* bsums   = (int*)alloc((size_t)64 * 4);
  int* csr     = (int*)alloc((size_t)Etot * 4);

  hipMemsetAsync(counts, 0, (size_t)N_NODES * 4, stream);
  hipMemsetAsync(cursor, 0, (size_t)N_NODES * 4, stream);

  // ---- prep: bf16 conversions ----
  int n4 = N_NODES * 128 / 4;
  conv_x_kernel<<<(n4 + 255) / 256, 256, 0, stream>>>(x, xb, n4);
  convT_kernel<<<(128 * 256 + 255) / 256, 256, 0, stream>>>(W0, W0T, 128, 256);
  convT_kernel<<<(256 * 128 + 255) / 256, 256, 0, stream>>>(W1, W1T, 256, 128);

  // ---- CSR build (shared by both layers) ----
  const int nblk = (N_NODES + 1023) / 1024;  // 49
  hist_kernel<<<(Etot + 255) / 256, 256, 0, stream>>>(ei, E, Etot, counts);
  scan1_kernel<<<nblk, 1024, 0, stream>>>(counts, partial, bsums, N_NODES);
  scan2_kernel<<<1, 64, 0, stream>>>(bsums, nblk);
  scan3_kernel<<<(N_NODES + 255) / 256, 256, 0, stream>>>(partial, bsums, rowptr, N_NODES);
  scatter_kernel<<<(Etot + 255) / 256, 256, 0, stream>>>(ei, E, Etot, rowptr, cursor, csr);

  // ---- layer 0 ----
  dim3 g0((N_NODES + 63) / 64, 256 / 64);
  gemm_mfma<<<g0, 256, 0, stream>>>(xb, W0T, h0b, N_NODES, 256, 128);
  scores_kernel<256><<<N_NODES, 256, 0, stream>>>(h0b, a_src0, a_dst0, ss0, sd0);
  agg0_kernel<<<N_NODES, 64, 0, stream>>>(h0b, ss0, sd0, rowptr, csr, b0, hEb);

  // ---- layer 1 ----
  dim3 g1((N_NODES + 63) / 64, 128 / 64);
  gemm_mfma<<<g1, 256, 0, stream>>>(hEb, W1T, h1b, N_NODES, 128, 256);
  scores_kernel<128><<<N_NODES, 128, 0, stream>>>(h1b, a_src1, a_dst1, ss1, sd1);
  agg1_kernel<<<N_NODES, 64, 0, stream>>>(h1b, ss1, sd1, rowptr, csr, b1,
                                          (const float2*)x, (float2*)out);
}

// Round 4
// 346.806 us; speedup vs baseline: 1.7416x; 1.1080x over previous
//
#include <hip/hip_runtime.h>

#define N_NODES 50000
#define NEG_SLOPE 0.2f

typedef short s8v __attribute__((ext_vector_type(8)));
typedef float f4v __attribute__((ext_vector_type(4)));

// ---- bf16 helpers (RNE) ---------------------------------------------------
__device__ __forceinline__ ushort f2bf(float f) {
  union { float f; unsigned u; } v; v.f = f;
  return (ushort)((v.u + 0x7FFFu + ((v.u >> 16) & 1u)) >> 16);
}
__device__ __forceinline__ float bf2f(ushort h) {
  union { unsigned u; float f; } v; v.u = ((unsigned)h) << 16;
  return v.f;
}

// ---- fp32 -> bf16 bulk convert (x) ----------------------------------------
__global__ void conv_x_kernel(const float* __restrict__ in, ushort* __restrict__ out, int n4) {
  int i = blockIdx.x * blockDim.x + threadIdx.x;
  if (i >= n4) return;
  float4 v = reinterpret_cast<const float4*>(in)[i];
  ushort4 o; o.x = f2bf(v.x); o.y = f2bf(v.y); o.z = f2bf(v.z); o.w = f2bf(v.w);
  reinterpret_cast<ushort4*>(out)[i] = o;
}

// ---- weight transpose+convert: in[R][C] fp32 -> out[C][R] bf16 ------------
__global__ void convT_kernel(const float* __restrict__ in, ushort* __restrict__ out,
                             int R, int C) {
  int i = blockIdx.x * blockDim.x + threadIdx.x;
  if (i >= R * C) return;
  int r = i / C, c = i % C;
  out[c * R + r] = f2bf(in[i]);
}

// ---- MFMA GEMM + fused attention scores -----------------------------------
// C[M,N]=A[M,K]*B[K,N]; A bf16 [M,K], BT bf16 [N,K]. 64x64 tile, BK=128.
// Epilogue: ss[m,head] += <C_row_part, a_src>, sd likewise (atomic, fp32).
// Head is uniform per block: n-tile is 64 wide, heads are 128-aligned.
template <int HEADS>
__global__ __launch_bounds__(256) void gemm_mfma(
    const ushort* __restrict__ A, const ushort* __restrict__ BT,
    ushort* __restrict__ C, int M, int N, int K,
    const float* __restrict__ a_src, const float* __restrict__ a_dst,
    float* __restrict__ ss, float* __restrict__ sd) {
  __shared__ ushort As[64][136];  // +8 pad: 16B-aligned, 2-way banks (free)
  __shared__ ushort Bs[64][136];
  const int tid = threadIdx.x;
  const int w = tid >> 6, lane = tid & 63;
  const int q = lane >> 4, r16 = lane & 15;
  const int m0 = blockIdx.x * 64, n0 = blockIdx.y * 64;
  f4v acc[4] = {};
  for (int kc = 0; kc < K; kc += 128) {
#pragma unroll
    for (int i = 0; i < 4; ++i) {
      int c = tid + 256 * i;
      int row = c >> 4, ko = (c & 15) * 8;
      int gm = m0 + row;
      s8v va = {};
      if (gm < M) va = *reinterpret_cast<const s8v*>(&A[(size_t)gm * K + kc + ko]);
      *reinterpret_cast<s8v*>(&As[row][ko]) = va;
      s8v vb = *reinterpret_cast<const s8v*>(&BT[(size_t)(n0 + row) * K + kc + ko]);
      *reinterpret_cast<s8v*>(&Bs[row][ko]) = vb;
    }
    __syncthreads();
#pragma unroll
    for (int ks = 0; ks < 4; ++ks) {
      s8v af = *reinterpret_cast<const s8v*>(&As[w * 16 + r16][ks * 32 + q * 8]);
#pragma unroll
      for (int nt = 0; nt < 4; ++nt) {
        s8v bf = *reinterpret_cast<const s8v*>(&Bs[nt * 16 + r16][ks * 32 + q * 8]);
        acc[nt] = __builtin_amdgcn_mfma_f32_16x16x32_bf16(af, bf, acc[nt], 0, 0, 0);
      }
    }
    __syncthreads();
  }
  // C store: D row=(lane>>4)*4+reg, col=lane&15
#pragma unroll
  for (int nt = 0; nt < 4; ++nt)
#pragma unroll
    for (int r = 0; r < 4; ++r) {
      int gm = m0 + w * 16 + q * 4 + r;
      if (gm < M) C[(size_t)gm * N + n0 + nt * 16 + r16] = f2bf(acc[nt][r]);
    }
  // fused scores epilogue
  const int head = n0 >> 7;  // 0 for N=128; 0/1 for N=256
  float ps[4] = {0.f, 0.f, 0.f, 0.f}, pd[4] = {0.f, 0.f, 0.f, 0.f};
#pragma unroll
  for (int nt = 0; nt < 4; ++nt) {
    int n = n0 + nt * 16 + r16;
    float as = a_src[n], ad = a_dst[n];
#pragma unroll
    for (int r = 0; r < 4; ++r) {
      ps[r] = fmaf(acc[nt][r], as, ps[r]);
      pd[r] = fmaf(acc[nt][r], ad, pd[r]);
    }
  }
#pragma unroll
  for (int off = 1; off < 16; off <<= 1) {
#pragma unroll
    for (int r = 0; r < 4; ++r) {
      ps[r] += __shfl_xor(ps[r], off);
      pd[r] += __shfl_xor(pd[r], off);
    }
  }
  if (r16 == 0) {
#pragma unroll
    for (int r = 0; r < 4; ++r) {
      int gm = m0 + w * 16 + q * 4 + r;
      if (gm < M) {
        atomicAdd(&ss[gm * HEADS + head], ps[r]);
        atomicAdd(&sd[gm * HEADS + head], pd[r]);
      }
    }
  }
}

// ---------------- CSR build: histogram -> 3-pass scan -> scatter ------------
__global__ void hist_kernel(const int* __restrict__ ei, int E, int Etot,
                            int* __restrict__ counts) {
  int e = blockIdx.x * blockDim.x + threadIdx.x;
  if (e >= Etot) return;
  int d = (e < E) ? ei[E + e] : (e - E);
  atomicAdd(&counts[d], 1);
}

__global__ __launch_bounds__(1024) void scan1_kernel(const int* __restrict__ counts,
                                                     int* __restrict__ partial,
                                                     int* __restrict__ blocksums, int n) {
  __shared__ int tmp[1024];
  int i = blockIdx.x * 1024 + threadIdx.x;
  int v = (i < n) ? counts[i] : 0;
  tmp[threadIdx.x] = v;
  __syncthreads();
  for (int off = 1; off < 1024; off <<= 1) {
    int t = (threadIdx.x >= off) ? tmp[threadIdx.x - off] : 0;
    __syncthreads();
    tmp[threadIdx.x] += t;
    __syncthreads();
  }
  if (i < n) partial[i] = tmp[threadIdx.x];
  if (threadIdx.x == 1023) blocksums[blockIdx.x] = tmp[1023];
}

__global__ __launch_bounds__(64) void scan2_kernel(int* __restrict__ blocksums, int nb) {
  int t = threadIdx.x;
  int v = (t < nb) ? blocksums[t] : 0;
#pragma unroll
  for (int off = 1; off < 64; off <<= 1) {
    int u = __shfl_up(v, off);
    if (t >= off) v += u;
  }
  if (t < nb) blocksums[t] = v;
}

__global__ void scan3_kernel(const int* __restrict__ partial,
                             const int* __restrict__ blocksums,
                             int* __restrict__ rowptr, int n) {
  int i = blockIdx.x * blockDim.x + threadIdx.x;
  if (i == 0) rowptr[0] = 0;
  if (i < n) {
    int b = i >> 10;
    int add = (b > 0) ? blocksums[b - 1] : 0;
    rowptr[i + 1] = partial[i] + add;
  }
}

__global__ void scatter_kernel(const int* __restrict__ ei, int E, int Etot,
                               const int* __restrict__ rowptr,
                               int* __restrict__ cursor,
                               int* __restrict__ csr_src, int* __restrict__ csr_dst) {
  int e = blockIdx.x * blockDim.x + threadIdx.x;
  if (e >= Etot) return;
  int s, d;
  if (e < E) { s = ei[e]; d = ei[E + e]; } else { s = d = e - E; }
  int pos = rowptr[d] + atomicAdd(&cursor[d], 1);
  csr_src[pos] = s;
  csr_dst[pos] = d;
}

// ---- edge weights: w[p,h] = exp(leakyrelu(ss[src,h]+sd[dst,h])) -----------
// score arrays are ~400 KB -> L2-resident gathers; no max-subtraction needed
// (softmax shift-invariant, scores bounded small).
template <int HEADS>
__global__ void ew_kernel(const int* __restrict__ csr_src, const int* __restrict__ csr_dst,
                          const float* __restrict__ ss, const float* __restrict__ sd,
                          float* __restrict__ wv, int Etot) {
  int p = blockIdx.x * blockDim.x + threadIdx.x;
  if (p >= Etot) return;
  int s = csr_src[p], d = csr_dst[p];
#pragma unroll
  for (int h = 0; h < HEADS; ++h) {
    float e = ss[s * HEADS + h] + sd[d * HEADS + h];
    e = (e > 0.f) ? e : NEG_SLOPE * e;
    wv[p * HEADS + h] = __expf(e);
  }
}

// ---- layer-0 aggregation (bf16 gather, precomputed w) + bias + ELU --------
__global__ __launch_bounds__(64) void agg0_kernel(
    const ushort* __restrict__ h0,  // [N,256] bf16
    const float* __restrict__ wv,   // [Etot,2]
    const int* __restrict__ rowptr, const int* __restrict__ csr_src,
    const float* __restrict__ b0, ushort* __restrict__ hE) {
  const int n = blockIdx.x, t = threadIdx.x;
  const int hd = t >> 5;
  float a0 = 0.f, a1 = 0.f, a2 = 0.f, a3 = 0.f, den = 0.f;
  int p = rowptr[n];
  const int p1 = rowptr[n + 1];
  for (; p + 2 <= p1; p += 2) {  // 2 rows in flight per wave
    const int sA = csr_src[p], sB = csr_src[p + 1];
    const float wA = wv[p * 2 + hd], wB = wv[p * 2 + 2 + hd];
    const ushort4 hA = *reinterpret_cast<const ushort4*>(&h0[(size_t)sA * 256 + t * 4]);
    const ushort4 hB = *reinterpret_cast<const ushort4*>(&h0[(size_t)sB * 256 + t * 4]);
    den += wA + wB;
    a0 = fmaf(wA, bf2f(hA.x), a0); a1 = fmaf(wA, bf2f(hA.y), a1);
    a2 = fmaf(wA, bf2f(hA.z), a2); a3 = fmaf(wA, bf2f(hA.w), a3);
    a0 = fmaf(wB, bf2f(hB.x), a0); a1 = fmaf(wB, bf2f(hB.y), a1);
    a2 = fmaf(wB, bf2f(hB.z), a2); a3 = fmaf(wB, bf2f(hB.w), a3);
  }
  if (p < p1) {
    const int sA = csr_src[p];
    const float wA = wv[p * 2 + hd];
    const ushort4 hA = *reinterpret_cast<const ushort4*>(&h0[(size_t)sA * 256 + t * 4]);
    den += wA;
    a0 = fmaf(wA, bf2f(hA.x), a0); a1 = fmaf(wA, bf2f(hA.y), a1);
    a2 = fmaf(wA, bf2f(hA.z), a2); a3 = fmaf(wA, bf2f(hA.w), a3);
  }
  const float inv = 1.f / den;
  const float4 bv = reinterpret_cast<const float4*>(b0)[t];
  float o[4] = {fmaf(a0, inv, bv.x), fmaf(a1, inv, bv.y),
                fmaf(a2, inv, bv.z), fmaf(a3, inv, bv.w)};
#pragma unroll
  for (int i = 0; i < 4; ++i) o[i] = (o[i] > 0.f) ? o[i] : (__expf(o[i]) - 1.f);
  ushort4 ov; ov.x = f2bf(o[0]); ov.y = f2bf(o[1]); ov.z = f2bf(o[2]); ov.w = f2bf(o[3]);
  *reinterpret_cast<ushort4*>(&hE[(size_t)n * 256 + t * 4]) = ov;
}

// ---- layer-1 aggregation (bf16 gather, precomputed w) + bias + residual ---
__global__ __launch_bounds__(64) void agg1_kernel(
    const ushort* __restrict__ h1,  // [N,128] bf16
    const float* __restrict__ wv,   // [Etot]
    const int* __restrict__ rowptr, const int* __restrict__ csr_src,
    const float* __restrict__ b1, const float2* __restrict__ x,
    float2* __restrict__ out) {
  const int n = blockIdx.x, t = threadIdx.x;
  float a0 = 0.f, a1 = 0.f, den = 0.f;
  int p = rowptr[n];
  const int p1 = rowptr[n + 1];
  for (; p + 2 <= p1; p += 2) {
    const int sA = csr_src[p], sB = csr_src[p + 1];
    const float wA = wv[p], wB = wv[p + 1];
    const ushort2 hA = *reinterpret_cast<const ushort2*>(&h1[(size_t)sA * 128 + t * 2]);
    const ushort2 hB = *reinterpret_cast<const ushort2*>(&h1[(size_t)sB * 128 + t * 2]);
    den += wA + wB;
    a0 = fmaf(wA, bf2f(hA.x), a0); a1 = fmaf(wA, bf2f(hA.y), a1);
    a0 = fmaf(wB, bf2f(hB.x), a0); a1 = fmaf(wB, bf2f(hB.y), a1);
  }
  if (p < p1) {
    const int sA = csr_src[p];
    const float wA = wv[p];
    const ushort2 hA = *reinterpret_cast<const ushort2*>(&h1[(size_t)sA * 128 + t * 2]);
    den += wA;
    a0 = fmaf(wA, bf2f(hA.x), a0); a1 = fmaf(wA, bf2f(hA.y), a1);
  }
  const float inv = 1.f / den;
  const float2 bv = reinterpret_cast<const float2*>(b1)[t];
  const float2 xv = x[(size_t)n * 64 + t];
  out[(size_t)n * 64 + t] =
      make_float2(xv.x + fmaf(a0, inv, bv.x), xv.y + fmaf(a1, inv, bv.y));
}

extern "C" void kernel_launch(void* const* d_in, const int* in_sizes, int n_in,
                              void* d_out, int out_size, void* d_ws, size_t ws_size,
                              hipStream_t stream) {
  const float* x      = (const float*)d_in[0];
  const float* W0     = (const float*)d_in[1];
  const float* a_src0 = (const float*)d_in[2];
  const float* a_dst0 = (const float*)d_in[3];
  const float* b0     = (const float*)d_in[4];
  const float* W1     = (const float*)d_in[5];
  const float* a_src1 = (const float*)d_in[6];
  const float* a_dst1 = (const float*)d_in[7];
  const float* b1     = (const float*)d_in[8];
  const int*   ei     = (const int*)d_in[9];
  const int E = in_sizes[9] / 2;
  const int Etot = E + N_NODES;
  float* out = (float*)d_out;
  (void)n_in; (void)out_size; (void)ws_size;

  char* ws = (char*)d_ws;
  size_t off = 0;
  auto alloc = [&](size_t bytes) -> char* {
    char* p = ws + off;
    off += (bytes + 255) & ~(size_t)255;
    return p;
  };
  ushort* xb   = (ushort*)alloc((size_t)N_NODES * 128 * 2);
  ushort* h0b  = (ushort*)alloc((size_t)N_NODES * 256 * 2);
  ushort* hEb  = (ushort*)alloc((size_t)N_NODES * 256 * 2);
  ushort* h1b  = (ushort*)alloc((size_t)N_NODES * 128 * 2);
  ushort* W0T  = (ushort*)alloc((size_t)256 * 128 * 2);
  ushort* W1T  = (ushort*)alloc((size_t)128 * 256 * 2);
  // ---- contiguous zero-init region: [counts, cursor, ss0, sd0, ss1, sd1] --
  size_t zoff0 = off;
  int* counts  = (int*)alloc((size_t)N_NODES * 4);
  int* cursor  = (int*)alloc((size_t)N_NODES * 4);
  float* ss0   = (float*)alloc((size_t)N_NODES * 2 * 4);
  float* sd0   = (float*)alloc((size_t)N_NODES * 2 * 4);
  float* ss1   = (float*)alloc((size_t)N_NODES * 4);
  float* sd1   = (float*)alloc((size_t)N_NODES * 4);
  size_t zbytes = off - zoff0;
  int* rowptr  = (int*)alloc((size_t)(N_NODES + 1) * 4);
  int* partial = (int*)alloc((size_t)N_NODES * 4);
  int* bsums   = (int*)alloc((size_t)64 * 4);
  int* csr     = (int*)alloc((size_t)Etot * 4);
  int* csrd    = (int*)alloc((size_t)Etot * 4);
  float* w0    = (float*)alloc((size_t)Etot * 2 * 4);
  float* w1    = (float*)alloc((size_t)Etot * 4);

  hipMemsetAsync(ws + zoff0, 0, zbytes, stream);

  // ---- prep: bf16 conversions ----
  int n4 = N_NODES * 128 / 4;
  conv_x_kernel<<<(n4 + 255) / 256, 256, 0, stream>>>(x, xb, n4);
  convT_kernel<<<(128 * 256 + 255) / 256, 256, 0, stream>>>(W0, W0T, 128, 256);
  convT_kernel<<<(256 * 128 + 255) / 256, 256, 0, stream>>>(W1, W1T, 256, 128);

  // ---- CSR build (shared by both layers) ----
  const int nblk = (N_NODES + 1023) / 1024;  // 49
  hist_kernel<<<(Etot + 255) / 256, 256, 0, stream>>>(ei, E, Etot, counts);
  scan1_kernel<<<nblk, 1024, 0, stream>>>(counts, partial, bsums, N_NODES);
  scan2_kernel<<<1, 64, 0, stream>>>(bsums, nblk);
  scan3_kernel<<<(N_NODES + 255) / 256, 256, 0, stream>>>(partial, bsums, rowptr, N_NODES);
  scatter_kernel<<<(Etot + 255) / 256, 256, 0, stream>>>(ei, E, Etot, rowptr, cursor, csr, csrd);

  // ---- layer 0 ----
  dim3 g0((N_NODES + 63) / 64, 256 / 64);
  gemm_mfma<2><<<g0, 256, 0, stream>>>(xb, W0T, h0b, N_NODES, 256, 128,
                                       a_src0, a_dst0, ss0, sd0);
  ew_kernel<2><<<(Etot + 255) / 256, 256, 0, stream>>>(csr, csrd, ss0, sd0, w0, Etot);
  agg0_kernel<<<N_NODES, 64, 0, stream>>>(h0b, w0, rowptr, csr, b0, hEb);

  // ---- layer 1 ----
  dim3 g1((N_NODES + 63) / 64, 128 / 64);
  gemm_mfma<1><<<g1, 256, 0, stream>>>(hEb, W1T, h1b, N_NODES, 128, 256,
                                       a_src1, a_dst1, ss1, sd1);
  ew_kernel<1><<<(Etot + 255) / 256, 256, 0, stream>>>(csr, csrd, ss1, sd1, w1, Etot);
  agg1_kernel<<<N_NODES, 64, 0, stream>>>(h1b, w1, rowptr, csr, b1,
                                          (const float2*)x, (float2*)out);
}

// Round 5
// 305.158 us; speedup vs baseline: 1.9793x; 1.1365x over previous
//
#include <hip/hip_runtime.h>

#define N_NODES 50000
#define NEG_SLOPE 0.2f

typedef short s8v __attribute__((ext_vector_type(8)));
typedef float f4v __attribute__((ext_vector_type(4)));

// ---- bf16 helpers (RNE) ---------------------------------------------------
__device__ __forceinline__ ushort f2bf(float f) {
  union { float f; unsigned u; } v; v.f = f;
  return (ushort)((v.u + 0x7FFFu + ((v.u >> 16) & 1u)) >> 16);
}
__device__ __forceinline__ float bf2f(ushort h) {
  union { unsigned u; float f; } v; v.u = ((unsigned)h) << 16;
  return v.f;
}

// ---- fp32 -> bf16 bulk convert (x) ----------------------------------------
__global__ void conv_x_kernel(const float* __restrict__ in, ushort* __restrict__ out, int n4) {
  int i = blockIdx.x * blockDim.x + threadIdx.x;
  if (i >= n4) return;
  float4 v = reinterpret_cast<const float4*>(in)[i];
  ushort4 o; o.x = f2bf(v.x); o.y = f2bf(v.y); o.z = f2bf(v.z); o.w = f2bf(v.w);
  reinterpret_cast<ushort4*>(out)[i] = o;
}

// ---- weight transpose+convert: in[R][C] fp32 -> out[C][R] bf16 ------------
__global__ void convT_kernel(const float* __restrict__ in, ushort* __restrict__ out,
                             int R, int C) {
  int i = blockIdx.x * blockDim.x + threadIdx.x;
  if (i >= R * C) return;
  int r = i / C, c = i % C;
  out[c * R + r] = f2bf(in[i]);
}

// ---- MFMA GEMM + fused attention scores -----------------------------------
template <int HEADS>
__global__ __launch_bounds__(256) void gemm_mfma(
    const ushort* __restrict__ A, const ushort* __restrict__ BT,
    ushort* __restrict__ C, int M, int N, int K,
    const float* __restrict__ a_src, const float* __restrict__ a_dst,
    float* __restrict__ ss, float* __restrict__ sd) {
  __shared__ ushort As[64][136];  // +8 pad: 16B-aligned, 2-way banks (free)
  __shared__ ushort Bs[64][136];
  const int tid = threadIdx.x;
  const int w = tid >> 6, lane = tid & 63;
  const int q = lane >> 4, r16 = lane & 15;
  const int m0 = blockIdx.x * 64, n0 = blockIdx.y * 64;
  f4v acc[4] = {};
  for (int kc = 0; kc < K; kc += 128) {
#pragma unroll
    for (int i = 0; i < 4; ++i) {
      int c = tid + 256 * i;
      int row = c >> 4, ko = (c & 15) * 8;
      int gm = m0 + row;
      s8v va = {};
      if (gm < M) va = *reinterpret_cast<const s8v*>(&A[(size_t)gm * K + kc + ko]);
      *reinterpret_cast<s8v*>(&As[row][ko]) = va;
      s8v vb = *reinterpret_cast<const s8v*>(&BT[(size_t)(n0 + row) * K + kc + ko]);
      *reinterpret_cast<s8v*>(&Bs[row][ko]) = vb;
    }
    __syncthreads();
#pragma unroll
    for (int ks = 0; ks < 4; ++ks) {
      s8v af = *reinterpret_cast<const s8v*>(&As[w * 16 + r16][ks * 32 + q * 8]);
#pragma unroll
      for (int nt = 0; nt < 4; ++nt) {
        s8v bf = *reinterpret_cast<const s8v*>(&Bs[nt * 16 + r16][ks * 32 + q * 8]);
        acc[nt] = __builtin_amdgcn_mfma_f32_16x16x32_bf16(af, bf, acc[nt], 0, 0, 0);
      }
    }
    __syncthreads();
  }
  // C store: D row=(lane>>4)*4+reg, col=lane&15
#pragma unroll
  for (int nt = 0; nt < 4; ++nt)
#pragma unroll
    for (int r = 0; r < 4; ++r) {
      int gm = m0 + w * 16 + q * 4 + r;
      if (gm < M) C[(size_t)gm * N + n0 + nt * 16 + r16] = f2bf(acc[nt][r]);
    }
  // fused scores epilogue (head uniform per block: n-tile 64-wide, heads 128-aligned)
  const int head = n0 >> 7;
  float ps[4] = {0.f, 0.f, 0.f, 0.f}, pd[4] = {0.f, 0.f, 0.f, 0.f};
#pragma unroll
  for (int nt = 0; nt < 4; ++nt) {
    int n = n0 + nt * 16 + r16;
    float as = a_src[n], ad = a_dst[n];
#pragma unroll
    for (int r = 0; r < 4; ++r) {
      ps[r] = fmaf(acc[nt][r], as, ps[r]);
      pd[r] = fmaf(acc[nt][r], ad, pd[r]);
    }
  }
#pragma unroll
  for (int off = 1; off < 16; off <<= 1) {
#pragma unroll
    for (int r = 0; r < 4; ++r) {
      ps[r] += __shfl_xor(ps[r], off);
      pd[r] += __shfl_xor(pd[r], off);
    }
  }
  if (r16 == 0) {
#pragma unroll
    for (int r = 0; r < 4; ++r) {
      int gm = m0 + w * 16 + q * 4 + r;
      if (gm < M) {
        atomicAdd(&ss[gm * HEADS + head], ps[r]);
        atomicAdd(&sd[gm * HEADS + head], pd[r]);
      }
    }
  }
}

// ------------- CSR build: hist(+rank) -> 3-pass scan -> scatter -------------
// hist's atomicAdd return IS the edge's rank within its dst bucket.
__global__ void hist_kernel(const int* __restrict__ ei, int E, int Etot,
                            int* __restrict__ counts, int* __restrict__ rank) {
  int e = blockIdx.x * blockDim.x + threadIdx.x;
  if (e >= Etot) return;
  int d = (e < E) ? ei[E + e] : (e - E);
  rank[e] = atomicAdd(&counts[d], 1);
}

__global__ __launch_bounds__(1024) void scan1_kernel(const int* __restrict__ counts,
                                                     int* __restrict__ partial,
                                                     int* __restrict__ blocksums, int n) {
  __shared__ int tmp[1024];
  int i = blockIdx.x * 1024 + threadIdx.x;
  int v = (i < n) ? counts[i] : 0;
  tmp[threadIdx.x] = v;
  __syncthreads();
  for (int off = 1; off < 1024; off <<= 1) {
    int t = (threadIdx.x >= off) ? tmp[threadIdx.x - off] : 0;
    __syncthreads();
    tmp[threadIdx.x] += t;
    __syncthreads();
  }
  if (i < n) partial[i] = tmp[threadIdx.x];
  if (threadIdx.x == 1023) blocksums[blockIdx.x] = tmp[1023];
}

__global__ __launch_bounds__(64) void scan2_kernel(int* __restrict__ blocksums, int nb) {
  int t = threadIdx.x;
  int v = (t < nb) ? blocksums[t] : 0;
#pragma unroll
  for (int off = 1; off < 64; off <<= 1) {
    int u = __shfl_up(v, off);
    if (t >= off) v += u;
  }
  if (t < nb) blocksums[t] = v;
}

__global__ void scan3_kernel(const int* __restrict__ partial,
                             const int* __restrict__ blocksums,
                             int* __restrict__ rowptr, int n) {
  int i = blockIdx.x * blockDim.x + threadIdx.x;
  if (i == 0) rowptr[0] = 0;
  if (i < n) {
    int b = i >> 10;
    int add = (b > 0) ? blocksums[b - 1] : 0;
    rowptr[i + 1] = partial[i] + add;
  }
}

// scatter: no atomics; one 8B packed write per edge (one random line touch)
__global__ void scatter_kernel(const int* __restrict__ ei, int E, int Etot,
                               const int* __restrict__ rowptr,
                               const int* __restrict__ rank,
                               unsigned long long* __restrict__ csr) {
  int e = blockIdx.x * blockDim.x + threadIdx.x;
  if (e >= Etot) return;
  int s, d;
  if (e < E) { s = ei[e]; d = ei[E + e]; } else { s = d = e - E; }
  int pos = rowptr[d] + rank[e];
  csr[pos] = ((unsigned long long)(unsigned)d << 32) | (unsigned)s;
}

// ---- edge weights: w[p,h] = exp(leakyrelu(ss[src,h]+sd[dst,h])) -----------
template <int HEADS>
__global__ void ew_kernel(const uint2* __restrict__ csr,
                          const float* __restrict__ ss, const float* __restrict__ sd,
                          float* __restrict__ wv, int Etot) {
  int p = blockIdx.x * blockDim.x + threadIdx.x;
  if (p >= Etot) return;
  uint2 e2 = csr[p];
  int s = (int)e2.x, d = (int)e2.y;
#pragma unroll
  for (int h = 0; h < HEADS; ++h) {
    float e = ss[s * HEADS + h] + sd[d * HEADS + h];
    e = (e > 0.f) ? e : NEG_SLOPE * e;
    wv[p * HEADS + h] = __expf(e);
  }
}

// ---- layer-0 aggregation (bf16 gather, 4-deep MLP) + bias + ELU -----------
__global__ __launch_bounds__(64) void agg0_kernel(
    const ushort* __restrict__ h0,  // [N,256] bf16
    const float* __restrict__ wv,   // [Etot,2]
    const int* __restrict__ rowptr, const uint2* __restrict__ csr,
    const float* __restrict__ b0, ushort* __restrict__ hE) {
  const int n = blockIdx.x, t = threadIdx.x;
  const int hd = t >> 5;
  float a0 = 0.f, a1 = 0.f, a2 = 0.f, a3 = 0.f, den = 0.f;
  int p = rowptr[n];
  const int p1 = rowptr[n + 1];
  for (; p + 4 <= p1; p += 4) {  // 4 rows in flight per wave
    const int s0 = (int)csr[p].x, s1 = (int)csr[p + 1].x;
    const int s2 = (int)csr[p + 2].x, s3 = (int)csr[p + 3].x;
    const float w0 = wv[p * 2 + hd],     w1 = wv[p * 2 + 2 + hd];
    const float w2 = wv[p * 2 + 4 + hd], w3 = wv[p * 2 + 6 + hd];
    const ushort4 v0 = *reinterpret_cast<const ushort4*>(&h0[(size_t)s0 * 256 + t * 4]);
    const ushort4 v1 = *reinterpret_cast<const ushort4*>(&h0[(size_t)s1 * 256 + t * 4]);
    const ushort4 v2 = *reinterpret_cast<const ushort4*>(&h0[(size_t)s2 * 256 + t * 4]);
    const ushort4 v3 = *reinterpret_cast<const ushort4*>(&h0[(size_t)s3 * 256 + t * 4]);
    den += (w0 + w1) + (w2 + w3);
    a0 = fmaf(w0, bf2f(v0.x), a0); a1 = fmaf(w0, bf2f(v0.y), a1);
    a2 = fmaf(w0, bf2f(v0.z), a2); a3 = fmaf(w0, bf2f(v0.w), a3);
    a0 = fmaf(w1, bf2f(v1.x), a0); a1 = fmaf(w1, bf2f(v1.y), a1);
    a2 = fmaf(w1, bf2f(v1.z), a2); a3 = fmaf(w1, bf2f(v1.w), a3);
    a0 = fmaf(w2, bf2f(v2.x), a0); a1 = fmaf(w2, bf2f(v2.y), a1);
    a2 = fmaf(w2, bf2f(v2.z), a2); a3 = fmaf(w2, bf2f(v2.w), a3);
    a0 = fmaf(w3, bf2f(v3.x), a0); a1 = fmaf(w3, bf2f(v3.y), a1);
    a2 = fmaf(w3, bf2f(v3.z), a2); a3 = fmaf(w3, bf2f(v3.w), a3);
  }
  for (; p < p1; ++p) {
    const int s0 = (int)csr[p].x;
    const float w0 = wv[p * 2 + hd];
    const ushort4 v0 = *reinterpret_cast<const ushort4*>(&h0[(size_t)s0 * 256 + t * 4]);
    den += w0;
    a0 = fmaf(w0, bf2f(v0.x), a0); a1 = fmaf(w0, bf2f(v0.y), a1);
    a2 = fmaf(w0, bf2f(v0.z), a2); a3 = fmaf(w0, bf2f(v0.w), a3);
  }
  const float inv = 1.f / den;
  const float4 bv = reinterpret_cast<const float4*>(b0)[t];
  float o[4] = {fmaf(a0, inv, bv.x), fmaf(a1, inv, bv.y),
                fmaf(a2, inv, bv.z), fmaf(a3, inv, bv.w)};
#pragma unroll
  for (int i = 0; i < 4; ++i) o[i] = (o[i] > 0.f) ? o[i] : (__expf(o[i]) - 1.f);
  ushort4 ov; ov.x = f2bf(o[0]); ov.y = f2bf(o[1]); ov.z = f2bf(o[2]); ov.w = f2bf(o[3]);
  *reinterpret_cast<ushort4*>(&hE[(size_t)n * 256 + t * 4]) = ov;
}

// ---- layer-1 aggregation (bf16 gather, 4-deep MLP) + bias + residual ------
__global__ __launch_bounds__(64) void agg1_kernel(
    const ushort* __restrict__ h1,  // [N,128] bf16
    const float* __restrict__ wv,   // [Etot]
    const int* __restrict__ rowptr, const uint2* __restrict__ csr,
    const float* __restrict__ b1, const float2* __restrict__ x,
    float2* __restrict__ out) {
  const int n = blockIdx.x, t = threadIdx.x;
  float a0 = 0.f, a1 = 0.f, den = 0.f;
  int p = rowptr[n];
  const int p1 = rowptr[n + 1];
  for (; p + 4 <= p1; p += 4) {
    const int s0 = (int)csr[p].x, s1 = (int)csr[p + 1].x;
    const int s2 = (int)csr[p + 2].x, s3 = (int)csr[p + 3].x;
    const float w0 = wv[p], w1 = wv[p + 1], w2 = wv[p + 2], w3 = wv[p + 3];
    const ushort2 v0 = *reinterpret_cast<const ushort2*>(&h1[(size_t)s0 * 128 + t * 2]);
    const ushort2 v1 = *reinterpret_cast<const ushort2*>(&h1[(size_t)s1 * 128 + t * 2]);
    const ushort2 v2 = *reinterpret_cast<const ushort2*>(&h1[(size_t)s2 * 128 + t * 2]);
    const ushort2 v3 = *reinterpret_cast<const ushort2*>(&h1[(size_t)s3 * 128 + t * 2]);
    den += (w0 + w1) + (w2 + w3);
    a0 = fmaf(w0, bf2f(v0.x), a0); a1 = fmaf(w0, bf2f(v0.y), a1);
    a0 = fmaf(w1, bf2f(v1.x), a0); a1 = fmaf(w1, bf2f(v1.y), a1);
    a0 = fmaf(w2, bf2f(v2.x), a0); a1 = fmaf(w2, bf2f(v2.y), a1);
    a0 = fmaf(w3, bf2f(v3.x), a0); a1 = fmaf(w3, bf2f(v3.y), a1);
  }
  for (; p < p1; ++p) {
    const int s0 = (int)csr[p].x;
    const float w0 = wv[p];
    const ushort2 v0 = *reinterpret_cast<const ushort2*>(&h1[(size_t)s0 * 128 + t * 2]);
    den += w0;
    a0 = fmaf(w0, bf2f(v0.x), a0); a1 = fmaf(w0, bf2f(v0.y), a1);
  }
  const float inv = 1.f / den;
  const float2 bv = reinterpret_cast<const float2*>(b1)[t];
  const float2 xv = x[(size_t)n * 64 + t];
  out[(size_t)n * 64 + t] =
      make_float2(xv.x + fmaf(a0, inv, bv.x), xv.y + fmaf(a1, inv, bv.y));
}

extern "C" void kernel_launch(void* const* d_in, const int* in_sizes, int n_in,
                              void* d_out, int out_size, void* d_ws, size_t ws_size,
                              hipStream_t stream) {
  const float* x      = (const float*)d_in[0];
  const float* W0     = (const float*)d_in[1];
  const float* a_src0 = (const float*)d_in[2];
  const float* a_dst0 = (const float*)d_in[3];
  const float* b0     = (const float*)d_in[4];
  const float* W1     = (const float*)d_in[5];
  const float* a_src1 = (const float*)d_in[6];
  const float* a_dst1 = (const float*)d_in[7];
  const float* b1     = (const float*)d_in[8];
  const int*   ei     = (const int*)d_in[9];
  const int E = in_sizes[9] / 2;
  const int Etot = E + N_NODES;
  float* out = (float*)d_out;
  (void)n_in; (void)out_size; (void)ws_size;

  char* ws = (char*)d_ws;
  size_t off = 0;
  auto alloc = [&](size_t bytes) -> char* {
    char* p = ws + off;
    off += (bytes + 255) & ~(size_t)255;
    return p;
  };
  ushort* xb   = (ushort*)alloc((size_t)N_NODES * 128 * 2);
  ushort* h0b  = (ushort*)alloc((size_t)N_NODES * 256 * 2);
  ushort* hEb  = (ushort*)alloc((size_t)N_NODES * 256 * 2);
  ushort* h1b  = (ushort*)alloc((size_t)N_NODES * 128 * 2);
  ushort* W0T  = (ushort*)alloc((size_t)256 * 128 * 2);
  ushort* W1T  = (ushort*)alloc((size_t)128 * 256 * 2);
  // ---- contiguous zero-init region: [counts, ss0, sd0, ss1, sd1] ----------
  size_t zoff0 = off;
  int* counts  = (int*)alloc((size_t)N_NODES * 4);
  float* ss0   = (float*)alloc((size_t)N_NODES * 2 * 4);
  float* sd0   = (float*)alloc((size_t)N_NODES * 2 * 4);
  float* ss1   = (float*)alloc((size_t)N_NODES * 4);
  float* sd1   = (float*)alloc((size_t)N_NODES * 4);
  size_t zbytes = off - zoff0;
  int* rowptr  = (int*)alloc((size_t)(N_NODES + 1) * 4);
  int* partial = (int*)alloc((size_t)N_NODES * 4);
  int* bsums   = (int*)alloc((size_t)64 * 4);
  int* rank    = (int*)alloc((size_t)Etot * 4);
  unsigned long long* csr = (unsigned long long*)alloc((size_t)Etot * 8);
  float* w0    = (float*)alloc((size_t)Etot * 2 * 4);
  float* w1    = (float*)alloc((size_t)Etot * 4);

  hipMemsetAsync(ws + zoff0, 0, zbytes, stream);

  // ---- prep: bf16 conversions ----
  int n4 = N_NODES * 128 / 4;
  conv_x_kernel<<<(n4 + 255) / 256, 256, 0, stream>>>(x, xb, n4);
  convT_kernel<<<(128 * 256 + 255) / 256, 256, 0, stream>>>(W0, W0T, 128, 256);
  convT_kernel<<<(256 * 128 + 255) / 256, 256, 0, stream>>>(W1, W1T, 256, 128);

  // ---- CSR build (shared by both layers) ----
  const int nblk = (N_NODES + 1023) / 1024;  // 49
  hist_kernel<<<(Etot + 255) / 256, 256, 0, stream>>>(ei, E, Etot, counts, rank);
  scan1_kernel<<<nblk, 1024, 0, stream>>>(counts, partial, bsums, N_NODES);
  scan2_kernel<<<1, 64, 0, stream>>>(bsums, nblk);
  scan3_kernel<<<(N_NODES + 255) / 256, 256, 0, stream>>>(partial, bsums, rowptr, N_NODES);
  scatter_kernel<<<(Etot + 255) / 256, 256, 0, stream>>>(ei, E, Etot, rowptr, rank, csr);

  // ---- layer 0 ----
  dim3 g0((N_NODES + 63) / 64, 256 / 64);
  gemm_mfma<2><<<g0, 256, 0, stream>>>(xb, W0T, h0b, N_NODES, 256, 128,
                                       a_src0, a_dst0, ss0, sd0);
  ew_kernel<2><<<(Etot + 255) / 256, 256, 0, stream>>>((const uint2*)csr, ss0, sd0, w0, Etot);
  agg0_kernel<<<N_NODES, 64, 0, stream>>>(h0b, w0, rowptr, (const uint2*)csr, b0, hEb);

  // ---- layer 1 ----
  dim3 g1((N_NODES + 63) / 64, 128 / 64);
  gemm_mfma<1><<<g1, 256, 0, stream>>>(hEb, W1T, h1b, N_NODES, 128, 256,
                                       a_src1, a_dst1, ss1, sd1);
  ew_kernel<1><<<(Etot + 255) / 256, 256, 0, stream>>>((const uint2*)csr, ss1, sd1, w1, Etot);
  agg1_kernel<<<N_NODES, 64, 0, stream>>>(h1b, w1, rowptr, (const uint2*)csr, b1,
                                          (const float2*)x, (float2*)out);
}